// Round 5
// baseline (98.243 us; speedup 1.0000x reference)
//
#include <hip/hip_runtime.h>

#define N_REGIONS 17
#define N_CH 7
#define ROWS_ 82
#define COLS_ 67
#define N_MAP (ROWS_ * COLS_)        // 5494 cells in the grid
#define EPB (N_MAP * N_CH)           // 38458 floats per batch (== 2 mod 4)
#define PAIR (2 * EPB)               // 76916 floats per 2 batches (== 0 mod 4)
#define PAIR4 (PAIR / 4)             // 19229 float4s per pair
#define XROW (N_REGIONS * N_CH)      // 119 floats per batch of x
#define XPAIR (2 * XROW)             // 238 floats of x per pair
#define LDSF 8192                    // padded to 256 idx slots * 32 banks = 32 KB

typedef float f32x4 __attribute__((ext_vector_type(4)));

// total output = 2048 * 38458 = 1024 * 76916 = 78,761,984 floats (exact)

__global__ void init_table_k(short* __restrict__ t) {
    int i = blockIdx.x * blockDim.x + threadIdx.x;
    if (i < PAIR) t[i] = -1;
}

__global__ void scatter_table_k(const int* __restrict__ cell_lin,
                                const int* __restrict__ region_ids,
                                int n, short* __restrict__ t) {
    int i = blockIdx.x * blockDim.x + threadIdx.x;
    if (i >= n) return;
    int c = cell_lin[i];
    int r = region_ids[i];
    if (c < 0 || c >= N_MAP) return;
#pragma unroll
    for (int lb = 0; lb < 2; ++lb) {
        int dst = lb * EPB + c * N_CH;
        short src = (short)(lb * XROW + r * N_CH);
#pragma unroll
        for (int ch = 0; ch < N_CH; ++ch) t[dst + ch] = (short)(src + ch);
    }
}

// One block per pair. x[pair] replicated 32x across LDS banks:
// xsr[idx*32 + bank] == xp[idx]  ->  lane reads only its own bank, conflict-free.
__global__ __launch_bounds__(512) void fill4_k(const float* __restrict__ x,
                                               const short* __restrict__ t,
                                               float* __restrict__ out) {
    __shared__ float xsr[LDSF];
    unsigned pair = blockIdx.x;
    unsigned tid = threadIdx.x;
    const float* xp = x + (size_t)pair * XPAIR;
    for (unsigned j = tid; j < XPAIR * 32u; j += 512u)
        xsr[j] = xp[j >> 5];          // broadcast-friendly: 32 consecutive j share one idx
    __syncthreads();

    unsigned bank = tid & 31u;
    float* outp = out + (size_t)pair * PAIR;
    for (unsigned i = tid; i < PAIR4; i += 512u) {
        unsigned e0 = i * 4u;
        short4 s = *reinterpret_cast<const short4*>(t + e0);   // 8B coalesced, L2-resident
        // sentinel -1 -> idx 255 -> in-bounds pad slot; value discarded by select
        unsigned ax = ((unsigned)(s.x & 255) << 5) | bank;
        unsigned ay = ((unsigned)(s.y & 255) << 5) | bank;
        unsigned az = ((unsigned)(s.z & 255) << 5) | bank;
        unsigned aw = ((unsigned)(s.w & 255) << 5) | bank;
        f32x4 v;
        v.x = (s.x >= 0) ? xsr[ax] : 0.0f;
        v.y = (s.y >= 0) ? xsr[ay] : 0.0f;
        v.z = (s.z >= 0) ? xsr[az] : 0.0f;
        v.w = (s.w >= 0) ? xsr[aw] : 0.0f;
        __builtin_nontemporal_store(v, reinterpret_cast<f32x4*>(outp + e0));
    }
}

extern "C" void kernel_launch(void* const* d_in, const int* in_sizes, int n_in,
                              void* d_out, int out_size, void* d_ws, size_t ws_size,
                              hipStream_t stream) {
    const float* x        = (const float*)d_in[0];
    const int* cell_lin   = (const int*)d_in[1];
    const int* region_ids = (const int*)d_in[2];
    float* out = (float*)d_out;
    short* table = (short*)d_ws;          // 76916 * 2 B = 150 KB of scratch
    int n_cells = in_sizes[1];

    init_table_k<<<(PAIR + 255) / 256, 256, 0, stream>>>(table);
    scatter_table_k<<<(n_cells + 255) / 256, 256, 0, stream>>>(cell_lin, region_ids, n_cells, table);

    fill4_k<<<1024, 512, 0, stream>>>(x, table, out);
}